// Round 11
// baseline (143.283 us; speedup 1.0000x reference)
//
#include <hip/hip_runtime.h>
#include <hip/hip_bf16.h>
#include <cstdint>
#include <cstddef>

typedef float  f32x4  __attribute__((ext_vector_type(4)));
typedef __bf16 bf16x8 __attribute__((ext_vector_type(8)));

#define LOG2E 1.4426950408889634f

static constexpr int GN   = 8192;   // nodes
static constexpr int GIN  = 512;    // in features
static constexpr int GOUT = 256;    // out features

// ---------------- async global->LDS (width 16) ----------------
static __device__ __forceinline__ void gload_lds16(const void* g, void* lds){
  typedef uint32_t __attribute__((address_space(1)))* gp_t;
  typedef uint32_t __attribute__((address_space(3)))* lp_t;
  __builtin_amdgcn_global_load_lds((gp_t)(uintptr_t)g,
                                   (lp_t)(uint32_t)(uintptr_t)lds, 16, 0, 0);
}

// ================= L1: [wal/war: 128 blk][W-transpose: 32 blk][h->bf16: 2048 blk] ====
__global__ __launch_bounds__(256) void k_pre1(const float* __restrict__ W,
                                              const float* __restrict__ al,
                                              const float* __restrict__ ar,
                                              const float* __restrict__ h,
                                              float* __restrict__ wal,
                                              float* __restrict__ war,
                                              __bf16* __restrict__ WT,
                                              __bf16* __restrict__ hb){
  __shared__ float T[64][65];
  const int bid = blockIdx.x, tid = threadIdx.x;
  if(bid < 128){
    const int k = bid*4 + (tid>>6), lane = tid & 63;
    float4 wv = ((const float4*)(W + (size_t)k*GOUT))[lane];
    float4 av = ((const float4*)al)[lane];
    float4 bv = ((const float4*)ar)[lane];
    float sl = wv.x*av.x + wv.y*av.y + wv.z*av.z + wv.w*av.w;
    float sr = wv.x*bv.x + wv.y*bv.y + wv.z*bv.z + wv.w*bv.w;
    #pragma unroll
    for(int o=32;o;o>>=1){ sl += __shfl_down(sl,o,64); sr += __shfl_down(sr,o,64); }
    if(lane==0){ wal[k] = sl*LOG2E; war[k] = sr*LOG2E; }
  } else if(bid < 160){
    const int tile = bid - 128;
    const int k0 = (tile>>2)*64, c0 = (tile&3)*64;
    const int r = tid>>2, cs = (tid&3)*16;
    #pragma unroll
    for(int j=0;j<4;j++){
      float4 v = *(const float4*)(W + (size_t)(k0+r)*GOUT + c0 + cs + 4*j);
      T[r][cs+4*j+0]=v.x; T[r][cs+4*j+1]=v.y; T[r][cs+4*j+2]=v.z; T[r][cs+4*j+3]=v.w;
    }
    __syncthreads();
    bf16x8 o1, o2;
    #pragma unroll
    for(int j=0;j<8;j++){ o1[j]=(__bf16)T[cs+j][r]; o2[j]=(__bf16)T[cs+8+j][r]; }
    __bf16* dst = WT + (size_t)(c0+r)*GIN + k0 + cs;
    *(bf16x8*)dst = o1;
    *(bf16x8*)(dst+8) = o2;
  } else {
    size_t i = ((size_t)(bid-160)*256 + tid)*8;
    float4 v0 = *(const float4*)(h+i);
    float4 v1 = *(const float4*)(h+i+4);
    bf16x8 o;
    o[0]=(__bf16)v0.x; o[1]=(__bf16)v0.y; o[2]=(__bf16)v0.z; o[3]=(__bf16)v0.w;
    o[4]=(__bf16)v1.x; o[5]=(__bf16)v1.y; o[6]=(__bf16)v1.z; o[7]=(__bf16)v1.w;
    *(bf16x8*)(hb+i) = o;
  }
}

// ================= L2: [gemmT: 256][Wh12: 2048] (pack moved into k_attn) ============
__global__ __launch_bounds__(256) void k_pre2(const __bf16* __restrict__ WT,
                                              const __bf16* __restrict__ hb,
                                              __bf16* __restrict__ WhbT,
                                              const float* __restrict__ h,
                                              const float* __restrict__ wal,
                                              const float* __restrict__ war,
                                              float* __restrict__ Wh1,
                                              float* __restrict__ Wh2){
  __shared__ __attribute__((aligned(16))) __bf16 As[2][64*64];
  __shared__ __attribute__((aligned(16))) __bf16 Bs[2][128*64];
  const int bid = blockIdx.x, tid = threadIdx.x;
  const int lane = tid & 63, w = tid >> 6;

  if(bid < 256){
    // ---- gemmT: WhbT[m][n] = sum_k WT[m][k]*hb[n][k]
    const int mb = bid >> 6, nb = bid & 63;
    const int m0 = mb*64, n0 = nb*128;

    f32x4 acc[8];
    #pragma unroll
    for(int t=0;t<8;t++) acc[t] = (f32x4){0.f,0.f,0.f,0.f};

    const int lr = lane>>3;
    const int bs_sw = ((lane&7)*16) ^ (lr<<4);

    auto stage = [&](int it, int buf){
      const int k0b = it*128;
      #pragma unroll
      for(int s=0;s<6;s++){
        int u = w + s*4;
        const char* src; char* dst;
        if(u < 8){
          int r8 = u*8;
          src = (const char*)(WT + (size_t)(m0 + r8 + lr)*GIN);
          dst = (char*)&As[buf][0] + r8*128;
        } else {
          int r8 = (u-8)*8;
          src = (const char*)(hb + (size_t)(n0 + r8 + lr)*GIN);
          dst = (char*)&Bs[buf][0] + r8*128;
        }
        gload_lds16(src + k0b + bs_sw, dst);
      }
    };

    auto kstep = [&](int kk, int buf){
      const int ko = kk*64 + (lane>>4)*16;
      const int am = 16*w + (lane&15);
      bf16x8 af = *(const bf16x8*)((const char*)&As[buf][0] + am*128 + (ko ^ ((am&7)<<4)));
      #pragma unroll
      for(int t=0;t<8;t++){
        int n = 16*t + (lane&15);
        bf16x8 bf = *(const bf16x8*)((const char*)&Bs[buf][0] + n*128 + (ko ^ ((n&7)<<4)));
        acc[t] = __builtin_amdgcn_mfma_f32_16x16x32_bf16(af, bf, acc[t], 0, 0, 0);
      }
    };

    stage(0,0);
    asm volatile("s_waitcnt vmcnt(0)" ::: "memory");
    __builtin_amdgcn_s_barrier();
    for(int it=0; it<8; it++){
      int buf = it & 1;
      if(it < 7) stage(it+1, buf^1);
      kstep(0, buf);
      kstep(1, buf);
      asm volatile("s_waitcnt vmcnt(0)" ::: "memory");
      __builtin_amdgcn_s_barrier();
    }

    const int mrow = m0 + 16*w + 4*(lane>>4);
    const int nc0  = n0 + (lane&15);
    #pragma unroll
    for(int t=0;t<8;t++){
      #pragma unroll
      for(int r=0;r<4;r++){
        WhbT[(size_t)(mrow + r)*GN + nc0 + 16*t] = (__bf16)acc[t][r];
      }
    }
  } else {
    // ---- Wh1/Wh2 fp32 row-dots (exact-path scores)
    const int row = (bid-256)*4 + w;
    const float4* hp = (const float4*)(h + (size_t)row*GIN);
    float4 v0 = hp[lane*2], v1 = hp[lane*2+1];
    float4 a0 = ((const float4*)wal)[lane*2], a1 = ((const float4*)wal)[lane*2+1];
    float4 b0 = ((const float4*)war)[lane*2], b1 = ((const float4*)war)[lane*2+1];
    float sl = v0.x*a0.x+v0.y*a0.y+v0.z*a0.z+v0.w*a0.w
             + v1.x*a1.x+v1.y*a1.y+v1.z*a1.z+v1.w*a1.w;
    float sr = v0.x*b0.x+v0.y*b0.y+v0.z*b0.z+v0.w*b0.w
             + v1.x*b1.x+v1.y*b1.y+v1.z*b1.z+v1.w*b1.w;
    #pragma unroll
    for(int of=32;of;of>>=1){ sl += __shfl_down(sl,of,64); sr += __shfl_down(sr,of,64); }
    if(lane==0){ Wh1[row]=sl; Wh2[row]=sr; }
  }
}

// ================= fused pack + masked-softmax-attention =================
// grid 512: rg=bid>>3 (64 rowgroups of 128), chunk=bid&7 (1024 cols; chunk->XCD).
// PROLOGUE now streams this block's adj panel (128x1024 = 512KB, coalesced 256B
// wave-loads, depth-1 ping-pong) and ballot-packs bits directly into mkL — no pk
// buffer, no separate pack kernel. Co-resident block's main loop (LDS/MFMA) overlaps
// this HBM streaming (m114). Main loop identical to r10 (verified).
template<bool PART>
__global__ __launch_bounds__(256,2) void k_attn(const int* __restrict__ adj,
                                                const __bf16* __restrict__ WhbT,
                                                const float* __restrict__ Wh1s,
                                                const float* __restrict__ Wh2s,
                                                float* __restrict__ pv_out,
                                                float* __restrict__ s_out){
  __shared__ __attribute__((aligned(16))) char Vs[2][16384];
  __shared__ __attribute__((aligned(16))) unsigned int mkL[32*128];
  __shared__ __attribute__((aligned(16))) float wh2L[1024];
  const int tid = threadIdx.x, lane = tid & 63, w = tid >> 6;
  const int rg = blockIdx.x >> 3, chunk = blockIdx.x & 7;
  const int r0 = rg * 128;
  const int j0 = chunk * 1024;
  const int la = lane & 15, kg = lane >> 4, kg8 = kg << 3;

  // ---- early reg-loads (wh2 strip + wh1) ----
  float4 wv = *(const float4*)(Wh2s + j0 + tid*4);
  const float wh1_0 = Wh1s[r0 + 16*w + la];        // pre-scaled by log2(e)
  const float wh1_1 = Wh1s[r0 + 16*w + la + 64];

  // V stage: linear LDS dest, inverse-swizzled global src (r9/r10 layout, verified)
  const int l_log = (lane&7) ^ (lane>>3);
  const char* wbase = (const char*)WhbT
                    + (size_t)(64*w + 2*(lane>>3) + (l_log>>2))*(GN*2)
                    + (size_t)(l_log&3)*16;
  auto stage = [&](int it, int buf){
    const size_t colb = (size_t)(j0 + it*32)*2;
    char* dst = &Vs[buf][0] + w*4096 + lane*16;
    #pragma unroll
    for(int s=0;s<4;s++){
      gload_lds16(wbase + (size_t)(16*s)*(GN*2) + colb, dst + s*1024);
    }
  };

  stage(0, 0);                       // V(0) rides along under the adj streaming below

  // ---- fused pack: wave w streams rows 32w..32w+31 x 1024 cols -> mkL bits ----
  {
    const size_t abase = (size_t)(r0 + 32*w)*GN + j0 + lane;
    const int idx = lane & 15;
    int aA[16], aB[16];
    auto mload = [&](int s, int (&a)[16]){
      const int g = s >> 4, jb = s & 15;
      const size_t o = abase + (size_t)(16*g)*GN + jb*64;
      #pragma unroll
      for(int r=0;r<16;r++) a[r] = adj[o + (size_t)r*GN];
    };
    auto mpack = [&](int s, int (&a)[16]){
      const int g = s >> 4, jb = s & 15;
      uint64_t b0 = __ballot(a[0]!=0),  b1 = __ballot(a[1]!=0);
      uint64_t b2 = __ballot(a[2]!=0),  b3 = __ballot(a[3]!=0);
      uint64_t b4 = __ballot(a[4]!=0),  b5 = __ballot(a[5]!=0);
      uint64_t b6 = __ballot(a[6]!=0),  b7 = __ballot(a[7]!=0);
      uint64_t b8 = __ballot(a[8]!=0),  b9 = __ballot(a[9]!=0);
      uint64_t bA = __ballot(a[10]!=0), bB = __ballot(a[11]!=0);
      uint64_t bC = __ballot(a[12]!=0), bD = __ballot(a[13]!=0);
      uint64_t bE = __ballot(a[14]!=0), bF = __ballot(a[15]!=0);
      uint64_t c0 = (idx&1)? b1:b0, c1 = (idx&1)? b3:b2;
      uint64_t c2 = (idx&1)? b5:b4, c3 = (idx&1)? b7:b6;
      uint64_t c4 = (idx&1)? b9:b8, c5 = (idx&1)? bB:bA;
      uint64_t c6 = (idx&1)? bD:bC, c7 = (idx&1)? bF:bE;
      uint64_t d0 = (idx&2)? c1:c0, d1 = (idx&2)? c3:c2;
      uint64_t d2 = (idx&2)? c5:c4, d3 = (idx&2)? c7:c6;
      uint64_t e0 = (idx&4)? d1:d0, e1 = (idx&4)? d3:d2;
      uint64_t v  = (idx&8)? e1:e0;
      unsigned int hword = (lane&16)? (unsigned int)(v>>32) : (unsigned int)v;
      if(lane < 32){
        mkL[(2*jb + (lane>>4))*128 + 32*w + 16*g + idx] = hword;
      }
    };
    mload(0, aA);
    #pragma unroll 1
    for(int sp=0; sp<16; ++sp){
      const int s0 = 2*sp, s1 = s0+1;
      mload(s1, aB);                  // prefetch odd batch (stays in flight over pack)
      mpack(s0, aA);
      if(sp < 15) mload(s1+1, aA);    // prefetch next even batch
      mpack(s1, aB);
    }
  }

  *(float4*)&wh2L[tid*4] = wv;

  f32x4 acc0[16], acc1[16];
  #pragma unroll
  for(int t=0;t<16;t++){ acc0[t] = (f32x4){0.f,0.f,0.f,0.f}; acc1[t] = (f32x4){0.f,0.f,0.f,0.f}; }
  f32x4 accs0 = (f32x4){0.f,0.f,0.f,0.f};
  f32x4 accs1 = (f32x4){0.f,0.f,0.f,0.f};
  bf16x8 ones;
  #pragma unroll
  for(int j=0;j<8;j++) ones[j] = (__bf16)1.0f;

  __syncthreads();                   // drains stage(0) + mask/wh2 LDS fills

  auto mkpa = [&](float wh1, unsigned m8, float4 w0, float4 w1) -> bf16x8 {
    bf16x8 pa;
    float y, p;
    y = wh1 + w0.x; y = fmaxf(y, 0.2f*y); p = exp2f(y); pa[0] = (__bf16)((m8    )&1 ? p : 0.f);
    y = wh1 + w0.y; y = fmaxf(y, 0.2f*y); p = exp2f(y); pa[1] = (__bf16)((m8>>1)&1 ? p : 0.f);
    y = wh1 + w0.z; y = fmaxf(y, 0.2f*y); p = exp2f(y); pa[2] = (__bf16)((m8>>2)&1 ? p : 0.f);
    y = wh1 + w0.w; y = fmaxf(y, 0.2f*y); p = exp2f(y); pa[3] = (__bf16)((m8>>3)&1 ? p : 0.f);
    y = wh1 + w1.x; y = fmaxf(y, 0.2f*y); p = exp2f(y); pa[4] = (__bf16)((m8>>4)&1 ? p : 0.f);
    y = wh1 + w1.y; y = fmaxf(y, 0.2f*y); p = exp2f(y); pa[5] = (__bf16)((m8>>5)&1 ? p : 0.f);
    y = wh1 + w1.z; y = fmaxf(y, 0.2f*y); p = exp2f(y); pa[6] = (__bf16)((m8>>6)&1 ? p : 0.f);
    y = wh1 + w1.w; y = fmaxf(y, 0.2f*y); p = exp2f(y); pa[7] = (__bf16)((m8>>7)&1 ? p : 0.f);
    return pa;
  };

  // per-lane read base into V tile (pair-row + XOR slot), +t*1024 folds to immediate
  const int rd_off = (la>>1)*128 + (((((la&1)<<2) | kg) ^ (la>>1)) << 4);

  auto kstep = [&](int it, int buf){
    unsigned int m0 = mkL[it*128 + 16*w + la];
    unsigned int m1 = mkL[it*128 + 16*w + la + 64];
    const float* wp = &wh2L[it*32 + kg8];
    float4 w0 = *(const float4*)wp;
    float4 w1 = *(const float4*)(wp + 4);
    bf16x8 pa0 = mkpa(wh1_0, (m0 >> kg8) & 0xffu, w0, w1);
    bf16x8 pa1 = mkpa(wh1_1, (m1 >> kg8) & 0xffu, w0, w1);
    const char* vb = &Vs[buf][0] + rd_off;
    #pragma unroll
    for(int t=0;t<16;t++){
      bf16x8 bv = *(const bf16x8*)(vb + t*1024);
      acc0[t] = __builtin_amdgcn_mfma_f32_16x16x32_bf16(pa0, bv, acc0[t], 0, 0, 0);
      acc1[t] = __builtin_amdgcn_mfma_f32_16x16x32_bf16(pa1, bv, acc1[t], 0, 0, 0);
    }
    accs0 = __builtin_amdgcn_mfma_f32_16x16x32_bf16(pa0, ones, accs0, 0, 0, 0);
    accs1 = __builtin_amdgcn_mfma_f32_16x16x32_bf16(pa1, ones, accs1, 0, 0, 0);
  };

  for(int it=0; it<32; it++){
    const int buf = it & 1;
    if(it < 31) stage(it+1, buf^1);    // only VM ops in the loop; async, never consumed
    kstep(it, buf);                    // pure LDS + VALU + MFMA
    asm volatile("s_waitcnt vmcnt(0)" ::: "memory");   // stage had a full kstep to land
    __builtin_amdgcn_s_barrier();
  }

  const int orow0 = r0 + 16*w + 4*kg;
  const int orow1 = orow0 + 64;
  const int ocol  = la;
  if constexpr (PART){
    float* pv = pv_out + (size_t)chunk*GN*GOUT;
    float* sp = s_out  + (size_t)chunk*GN;
    #pragma unroll
    for(int t=0;t<16;t++){
      #pragma unroll
      for(int r=0;r<4;r++){
        pv[(size_t)(orow0 + r)*GOUT + ocol + 16*t] = acc0[t][r];
        pv[(size_t)(orow1 + r)*GOUT + ocol + 16*t] = acc1[t][r];
      }
    }
    if(ocol == 0){
      #pragma unroll
      for(int r=0;r<4;r++){ sp[orow0 + r] = accs0[r]; sp[orow1 + r] = accs1[r]; }
    }
  } else {
    #pragma unroll
    for(int t=0;t<16;t++){
      #pragma unroll
      for(int r=0;r<4;r++){
        atomicAdd(pv_out + (size_t)(orow0 + r)*GOUT + ocol + 16*t, acc0[t][r]);
        atomicAdd(pv_out + (size_t)(orow1 + r)*GOUT + ocol + 16*t, acc1[t][r]);
      }
    }
    if(ocol == 0){
      #pragma unroll
      for(int r=0;r<4;r++){ atomicAdd(s_out + orow0 + r, accs0[r]); atomicAdd(s_out + orow1 + r, accs1[r]); }
    }
  }
}

// ---------------- epilogues ----------------
static __device__ __forceinline__ float elu1(float x){
  return x > 0.f ? x : (exp2f(x*LOG2E) - 1.f);
}

__global__ void k_reduce(const float* __restrict__ accP, const float* __restrict__ accSp,
                         float* __restrict__ out){
  size_t i = ((size_t)blockIdx.x*256 + threadIdx.x)*4;
  int row = (int)(i >> 8);
  float S = 0.f;
  #pragma unroll
  for(int c=0;c<8;c++) S += accSp[(size_t)c*GN + row];
  float4 s = {0.f,0.f,0.f,0.f};
  #pragma unroll
  for(int c=0;c<8;c++){
    float4 v = *(const float4*)(accP + (size_t)c*GN*GOUT + i);
    s.x += v.x; s.y += v.y; s.z += v.z; s.w += v.w;
  }
  float inv = 1.0f / S;
  float4 o;
  o.x = elu1(s.x*inv); o.y = elu1(s.y*inv); o.z = elu1(s.z*inv); o.w = elu1(s.w*inv);
  *(float4*)(out + i) = o;
}

__global__ void k_norm(const float* __restrict__ accPV, const float* __restrict__ accS,
                       float* __restrict__ out){
  size_t i = ((size_t)blockIdx.x*256 + threadIdx.x)*4;
  int row = (int)(i >> 8);
  float inv = 1.0f / accS[row];
  float4 v = *(const float4*)(accPV + i);
  float4 o;
  o.x = elu1(v.x*inv); o.y = elu1(v.y*inv); o.z = elu1(v.z*inv); o.w = elu1(v.w*inv);
  *(float4*)(out + i) = o;
}

// ---------------- launch ----------------
extern "C" void kernel_launch(void* const* d_in, const int* in_sizes, int n_in,
                              void* d_out, int out_size, void* d_ws, size_t ws_size,
                              hipStream_t stream){
  const float* h  = (const float*)d_in[0];
  const int*   adj= (const int*)  d_in[1];
  const float* W  = (const float*)d_in[2];
  const float* al = (const float*)d_in[3];
  const float* ar = (const float*)d_in[4];
  float* out = (float*)d_out;
  char* ws = (char*)d_ws;

  const size_t SZ_ACCP = (size_t)8*GN*GOUT*4;        // 67,108,864
  const size_t NEED_A  = SZ_ACCP + 4194304 + 32768 + 32768 + 262144; // 71,630,848

  if(ws_size >= NEED_A){
    float*  accP  = (float*) (ws);
    __bf16* hb    = (__bf16*)(ws);                       // alias (prep-only)
    __bf16* WT    = (__bf16*)(ws + 8388608);             // alias (prep-only)
    float*  wal   = (float*) (ws + 8650752);             // alias (prep-only)
    float*  war   = (float*) (ws + 8652800);             // alias (prep-only)
    __bf16* WhbT  = (__bf16*)(ws + SZ_ACCP);
    float*  Wh1   = (float*) (ws + SZ_ACCP + 4194304);
    float*  Wh2   = (float*) (ws + SZ_ACCP + 4227072);
    float*  accSp = (float*) (ws + SZ_ACCP + 4259840);

    k_pre1<<<2208, 256, 0, stream>>>(W, al, ar, h, wal, war, WT, hb);
    k_pre2<<<2304, 256, 0, stream>>>(WT, hb, WhbT, h, wal, war, Wh1, Wh2);
    k_attn<true><<<512, 256, 0, stream>>>(adj, WhbT, Wh1, Wh2, accP, accSp);
    k_reduce<<<2048, 256, 0, stream>>>(accP, accSp, out);
  } else {
    float*  accPV = (float*) (ws);                       //  8,388,608
    float*  accS  = (float*) (ws + 8388608);             //     32,768
    __bf16* hb    = (__bf16*)(ws + 8421376);             //  8,388,608
    __bf16* WT    = (__bf16*)(ws + 16809984);            //    262,144
    __bf16* WhbT  = (__bf16*)(ws + 17072128);            //  4,194,304
    float*  wal   = (float*) (ws + 21266432);
    float*  war   = (float*) (ws + 21268480);
    float*  Wh1   = (float*) (ws + 21270528);
    float*  Wh2   = (float*) (ws + 21303296);
    if(ws_size < 21336064) return;

    hipMemsetAsync(accPV, 0, 8388608 + 32768, stream);
    k_pre1<<<2208, 256, 0, stream>>>(W, al, ar, h, wal, war, WT, hb);
    k_pre2<<<2304, 256, 0, stream>>>(WT, hb, WhbT, h, wal, war, Wh1, Wh2);
    k_attn<false><<<512, 256, 0, stream>>>(adj, WhbT, Wh1, Wh2, accPV, accS);
    k_norm<<<2048, 256, 0, stream>>>(accPV, accS, out);
  }
}

// Round 12
// 129.787 us; speedup vs baseline: 1.1040x; 1.1040x over previous
//
#include <hip/hip_runtime.h>
#include <hip/hip_bf16.h>
#include <cstdint>
#include <cstddef>

typedef float  f32x4  __attribute__((ext_vector_type(4)));
typedef __bf16 bf16x8 __attribute__((ext_vector_type(8)));

#define LOG2E 1.4426950408889634f

static constexpr int GN   = 8192;   // nodes
static constexpr int GIN  = 512;    // in features
static constexpr int GOUT = 256;    // out features

// ---------------- async global->LDS (width 16) ----------------
static __device__ __forceinline__ void gload_lds16(const void* g, void* lds){
  typedef uint32_t __attribute__((address_space(1)))* gp_t;
  typedef uint32_t __attribute__((address_space(3)))* lp_t;
  __builtin_amdgcn_global_load_lds((gp_t)(uintptr_t)g,
                                   (lp_t)(uint32_t)(uintptr_t)lds, 16, 0, 0);
}

// ================= L1: [wal/war: 128 blk][W-transpose: 32 blk][h->bf16: 2048 blk] ====
__global__ __launch_bounds__(256) void k_pre1(const float* __restrict__ W,
                                              const float* __restrict__ al,
                                              const float* __restrict__ ar,
                                              const float* __restrict__ h,
                                              float* __restrict__ wal,
                                              float* __restrict__ war,
                                              __bf16* __restrict__ WT,
                                              __bf16* __restrict__ hb){
  __shared__ float T[64][65];
  const int bid = blockIdx.x, tid = threadIdx.x;
  if(bid < 128){
    const int k = bid*4 + (tid>>6), lane = tid & 63;
    float4 wv = ((const float4*)(W + (size_t)k*GOUT))[lane];
    float4 av = ((const float4*)al)[lane];
    float4 bv = ((const float4*)ar)[lane];
    float sl = wv.x*av.x + wv.y*av.y + wv.z*av.z + wv.w*av.w;
    float sr = wv.x*bv.x + wv.y*bv.y + wv.z*bv.z + wv.w*bv.w;
    #pragma unroll
    for(int o=32;o;o>>=1){ sl += __shfl_down(sl,o,64); sr += __shfl_down(sr,o,64); }
    if(lane==0){ wal[k] = sl*LOG2E; war[k] = sr*LOG2E; }
  } else if(bid < 160){
    const int tile = bid - 128;
    const int k0 = (tile>>2)*64, c0 = (tile&3)*64;
    const int r = tid>>2, cs = (tid&3)*16;
    #pragma unroll
    for(int j=0;j<4;j++){
      float4 v = *(const float4*)(W + (size_t)(k0+r)*GOUT + c0 + cs + 4*j);
      T[r][cs+4*j+0]=v.x; T[r][cs+4*j+1]=v.y; T[r][cs+4*j+2]=v.z; T[r][cs+4*j+3]=v.w;
    }
    __syncthreads();
    bf16x8 o1, o2;
    #pragma unroll
    for(int j=0;j<8;j++){ o1[j]=(__bf16)T[cs+j][r]; o2[j]=(__bf16)T[cs+8+j][r]; }
    __bf16* dst = WT + (size_t)(c0+r)*GIN + k0 + cs;
    *(bf16x8*)dst = o1;
    *(bf16x8*)(dst+8) = o2;
  } else {
    size_t i = ((size_t)(bid-160)*256 + tid)*8;
    float4 v0 = *(const float4*)(h+i);
    float4 v1 = *(const float4*)(h+i+4);
    bf16x8 o;
    o[0]=(__bf16)v0.x; o[1]=(__bf16)v0.y; o[2]=(__bf16)v0.z; o[3]=(__bf16)v0.w;
    o[4]=(__bf16)v1.x; o[5]=(__bf16)v1.y; o[6]=(__bf16)v1.z; o[7]=(__bf16)v1.w;
    *(bf16x8*)(hb+i) = o;
  }
}

// ================= L2: [gemmT: 256][Wh12: 2048] ============
__global__ __launch_bounds__(256) void k_pre2(const __bf16* __restrict__ WT,
                                              const __bf16* __restrict__ hb,
                                              __bf16* __restrict__ WhbT,
                                              const float* __restrict__ h,
                                              const float* __restrict__ wal,
                                              const float* __restrict__ war,
                                              float* __restrict__ Wh1,
                                              float* __restrict__ Wh2){
  __shared__ __attribute__((aligned(16))) __bf16 As[2][64*64];
  __shared__ __attribute__((aligned(16))) __bf16 Bs[2][128*64];
  const int bid = blockIdx.x, tid = threadIdx.x;
  const int lane = tid & 63, w = tid >> 6;

  if(bid < 256){
    const int mb = bid >> 6, nb = bid & 63;
    const int m0 = mb*64, n0 = nb*128;

    f32x4 acc[8];
    #pragma unroll
    for(int t=0;t<8;t++) acc[t] = (f32x4){0.f,0.f,0.f,0.f};

    const int lr = lane>>3;
    const int bs_sw = ((lane&7)*16) ^ (lr<<4);

    auto stage = [&](int it, int buf){
      const int k0b = it*128;
      #pragma unroll
      for(int s=0;s<6;s++){
        int u = w + s*4;
        const char* src; char* dst;
        if(u < 8){
          int r8 = u*8;
          src = (const char*)(WT + (size_t)(m0 + r8 + lr)*GIN);
          dst = (char*)&As[buf][0] + r8*128;
        } else {
          int r8 = (u-8)*8;
          src = (const char*)(hb + (size_t)(n0 + r8 + lr)*GIN);
          dst = (char*)&Bs[buf][0] + r8*128;
        }
        gload_lds16(src + k0b + bs_sw, dst);
      }
    };

    auto kstep = [&](int kk, int buf){
      const int ko = kk*64 + (lane>>4)*16;
      const int am = 16*w + (lane&15);
      bf16x8 af = *(const bf16x8*)((const char*)&As[buf][0] + am*128 + (ko ^ ((am&7)<<4)));
      #pragma unroll
      for(int t=0;t<8;t++){
        int n = 16*t + (lane&15);
        bf16x8 bf = *(const bf16x8*)((const char*)&Bs[buf][0] + n*128 + (ko ^ ((n&7)<<4)));
        acc[t] = __builtin_amdgcn_mfma_f32_16x16x32_bf16(af, bf, acc[t], 0, 0, 0);
      }
    };

    stage(0,0);
    asm volatile("s_waitcnt vmcnt(0)" ::: "memory");
    __builtin_amdgcn_s_barrier();
    for(int it=0; it<8; it++){
      int buf = it & 1;
      if(it < 7) stage(it+1, buf^1);
      kstep(0, buf);
      kstep(1, buf);
      asm volatile("s_waitcnt vmcnt(0)" ::: "memory");
      __builtin_amdgcn_s_barrier();
    }

    const int mrow = m0 + 16*w + 4*(lane>>4);
    const int nc0  = n0 + (lane&15);
    #pragma unroll
    for(int t=0;t<8;t++){
      #pragma unroll
      for(int r=0;r<4;r++){
        WhbT[(size_t)(mrow + r)*GN + nc0 + 16*t] = (__bf16)acc[t][r];
      }
    }
  } else {
    const int row = (bid-256)*4 + w;
    const float4* hp = (const float4*)(h + (size_t)row*GIN);
    float4 v0 = hp[lane*2], v1 = hp[lane*2+1];
    float4 a0 = ((const float4*)wal)[lane*2], a1 = ((const float4*)wal)[lane*2+1];
    float4 b0 = ((const float4*)war)[lane*2], b1 = ((const float4*)war)[lane*2+1];
    float sl = v0.x*a0.x+v0.y*a0.y+v0.z*a0.z+v0.w*a0.w
             + v1.x*a1.x+v1.y*a1.y+v1.z*a1.z+v1.w*a1.w;
    float sr = v0.x*b0.x+v0.y*b0.y+v0.z*b0.z+v0.w*b0.w
             + v1.x*b1.x+v1.y*b1.y+v1.z*b1.z+v1.w*b1.w;
    #pragma unroll
    for(int of=32;of;of>>=1){ sl += __shfl_down(sl,of,64); sr += __shfl_down(sr,of,64); }
    if(lane==0){ Wh1[row]=sl; Wh2[row]=sr; }
  }
}

// ================= fused pack + masked-softmax-attention =================
// grid 512: rg=bid>>3 (64 rowgroups of 128), chunk=bid&7 (1024 cols; chunk->XCD).
// PACK (prologue) now streams LINEARLY: per row, 4 contiguous int4 wave-loads
// (1KB each, 4KB/row) double-buffered -> DRAM-page-friendly bursts. Ballot-native
// mask word: bit 8b+a <-> col 32*jw + 4a + b. mkL store XOR-swizzled (row^jw) to
// avoid 32-way write conflicts; kstep reads with row^it (2-way, free) and extracts
// bits at compile-time positions 8*(e&3)+(e>>2) after one >>2kg shift.
// Main loop / V path / epilogue identical to r11 (verified).
template<bool PART>
__global__ __launch_bounds__(256,2) void k_attn(const int* __restrict__ adj,
                                                const __bf16* __restrict__ WhbT,
                                                const float* __restrict__ Wh1s,
                                                const float* __restrict__ Wh2s,
                                                float* __restrict__ pv_out,
                                                float* __restrict__ s_out){
  __shared__ __attribute__((aligned(16))) char Vs[2][16384];
  __shared__ __attribute__((aligned(16))) unsigned int mkL[32*128];
  __shared__ __attribute__((aligned(16))) float wh2L[1024];
  const int tid = threadIdx.x, lane = tid & 63, w = tid >> 6;
  const int rg = blockIdx.x >> 3, chunk = blockIdx.x & 7;
  const int r0 = rg * 128;
  const int j0 = chunk * 1024;
  const int la = lane & 15, kg = lane >> 4, kg8 = kg << 3;

  // ---- early reg-loads (wh2 strip + wh1) ----
  float4 wv = *(const float4*)(Wh2s + j0 + tid*4);
  const float wh1_0 = Wh1s[r0 + 16*w + la];        // pre-scaled by log2(e)
  const float wh1_1 = Wh1s[r0 + 16*w + la + 64];

  // V stage: linear LDS dest, inverse-swizzled global src (r9-r11 layout, verified)
  const int l_log = (lane&7) ^ (lane>>3);
  const char* wbase = (const char*)WhbT
                    + (size_t)(64*w + 2*(lane>>3) + (l_log>>2))*(GN*2)
                    + (size_t)(l_log&3)*16;
  auto stage = [&](int it, int buf){
    const size_t colb = (size_t)(j0 + it*32)*2;
    char* dst = &Vs[buf][0] + w*4096 + lane*16;
    #pragma unroll
    for(int s=0;s<4;s++){
      gload_lds16(wbase + (size_t)(16*s)*(GN*2) + colb, dst + s*1024);
    }
  };

  stage(0, 0);                       // V(0) rides along under the adj streaming below

  // ---- fused pack, linear-burst version ----
  {
    const size_t abase = (size_t)(r0 + 32*w)*GN + j0;
    const int idx = lane & 31;
    const int shift = (idx & 7) * 8;
    const bool qb0 = (idx >> 3) & 1, qb1 = (idx >> 4) & 1;
    int4 A0[4], A1[4];
    auto rload = [&](int r, int4 (&A)[4]){
      const int* p = adj + abase + (size_t)r*GN + lane*4;
      #pragma unroll
      for(int q=0;q<4;q++) A[q] = *(const int4*)(p + q*256);
    };
    auto rpack = [&](int r, int4 (&A)[4]){
      uint64_t B00 = __ballot(A[0].x!=0), B01 = __ballot(A[0].y!=0),
               B02 = __ballot(A[0].z!=0), B03 = __ballot(A[0].w!=0);
      uint64_t B10 = __ballot(A[1].x!=0), B11 = __ballot(A[1].y!=0),
               B12 = __ballot(A[1].z!=0), B13 = __ballot(A[1].w!=0);
      uint64_t B20 = __ballot(A[2].x!=0), B21 = __ballot(A[2].y!=0),
               B22 = __ballot(A[2].z!=0), B23 = __ballot(A[2].w!=0);
      uint64_t B30 = __ballot(A[3].x!=0), B31 = __ballot(A[3].y!=0),
               B32 = __ballot(A[3].z!=0), B33 = __ballot(A[3].w!=0);
      // lane idx: word jw=idx (cols 32*idx..+31), q=idx>>3 selects ballot set
      uint64_t u0 = qb1 ? (qb0? B30:B20) : (qb0? B10:B00);
      uint64_t u1 = qb1 ? (qb0? B31:B21) : (qb0? B11:B01);
      uint64_t u2 = qb1 ? (qb0? B32:B22) : (qb0? B12:B02);
      uint64_t u3 = qb1 ? (qb0? B33:B23) : (qb0? B13:B03);
      unsigned int word = ((unsigned int)(u0 >> shift) & 0xffu)
                        | (((unsigned int)(u1 >> shift) & 0xffu) << 8)
                        | (((unsigned int)(u2 >> shift) & 0xffu) << 16)
                        | (((unsigned int)(u3 >> shift) & 0xffu) << 24);
      if(lane < 32){
        const int row = 32*w + r;
        mkL[idx*128 + (row ^ idx)] = word;     // XOR-swizzle: store conflict-free
      }
    };
    rload(0, A0);
    #pragma unroll 1
    for(int rp=0; rp<16; ++rp){
      const int ra = 2*rp, rb = ra+1;
      rload(rb, A1);                  // prefetch odd row (in flight over pack)
      rpack(ra, A0);
      if(rp < 15) rload(rb+1, A0);    // prefetch next even row
      rpack(rb, A1);
    }
  }

  *(float4*)&wh2L[tid*4] = wv;

  f32x4 acc0[16], acc1[16];
  #pragma unroll
  for(int t=0;t<16;t++){ acc0[t] = (f32x4){0.f,0.f,0.f,0.f}; acc1[t] = (f32x4){0.f,0.f,0.f,0.f}; }
  f32x4 accs0 = (f32x4){0.f,0.f,0.f,0.f};
  f32x4 accs1 = (f32x4){0.f,0.f,0.f,0.f};
  bf16x8 ones;
  #pragma unroll
  for(int j=0;j<8;j++) ones[j] = (__bf16)1.0f;

  __syncthreads();                   // drains stage(0) + mask/wh2 LDS fills

  // ballot-native bit order: pa[e] <- bit 8*(e&3)+(e>>2) of (m32 >> 2kg)
  auto mkpa = [&](float wh1, unsigned mm, float4 w0, float4 w1) -> bf16x8 {
    bf16x8 pa;
    float y, p;
    y = wh1 + w0.x; y = fmaxf(y, 0.2f*y); p = exp2f(y); pa[0] = (__bf16)((mm    )&1 ? p : 0.f);
    y = wh1 + w0.y; y = fmaxf(y, 0.2f*y); p = exp2f(y); pa[1] = (__bf16)((mm>>8 )&1 ? p : 0.f);
    y = wh1 + w0.z; y = fmaxf(y, 0.2f*y); p = exp2f(y); pa[2] = (__bf16)((mm>>16)&1 ? p : 0.f);
    y = wh1 + w0.w; y = fmaxf(y, 0.2f*y); p = exp2f(y); pa[3] = (__bf16)((mm>>24)&1 ? p : 0.f);
    y = wh1 + w1.x; y = fmaxf(y, 0.2f*y); p = exp2f(y); pa[4] = (__bf16)((mm>>1 )&1 ? p : 0.f);
    y = wh1 + w1.y; y = fmaxf(y, 0.2f*y); p = exp2f(y); pa[5] = (__bf16)((mm>>9 )&1 ? p : 0.f);
    y = wh1 + w1.z; y = fmaxf(y, 0.2f*y); p = exp2f(y); pa[6] = (__bf16)((mm>>17)&1 ? p : 0.f);
    y = wh1 + w1.w; y = fmaxf(y, 0.2f*y); p = exp2f(y); pa[7] = (__bf16)((mm>>25)&1 ? p : 0.f);
    return pa;
  };

  // per-lane read base into V tile (pair-row + XOR slot), +t*1024 folds to immediate
  const int rd_off = (la>>1)*128 + (((((la&1)<<2) | kg) ^ (la>>1)) << 4);
  const int kg2 = 2*kg;

  auto kstep = [&](int it, int buf){
    unsigned int m0 = mkL[it*128 + ((16*w + la) ^ it)];
    unsigned int m1 = mkL[it*128 + ((16*w + la + 64) ^ it)];
    const float* wp = &wh2L[it*32 + kg8];
    float4 w0 = *(const float4*)wp;
    float4 w1 = *(const float4*)(wp + 4);
    bf16x8 pa0 = mkpa(wh1_0, m0 >> kg2, w0, w1);
    bf16x8 pa1 = mkpa(wh1_1, m1 >> kg2, w0, w1);
    const char* vb = &Vs[buf][0] + rd_off;
    #pragma unroll
    for(int t=0;t<16;t++){
      bf16x8 bv = *(const bf16x8*)(vb + t*1024);
      acc0[t] = __builtin_amdgcn_mfma_f32_16x16x32_bf16(pa0, bv, acc0[t], 0, 0, 0);
      acc1[t] = __builtin_amdgcn_mfma_f32_16x16x32_bf16(pa1, bv, acc1[t], 0, 0, 0);
    }
    accs0 = __builtin_amdgcn_mfma_f32_16x16x32_bf16(pa0, ones, accs0, 0, 0, 0);
    accs1 = __builtin_amdgcn_mfma_f32_16x16x32_bf16(pa1, ones, accs1, 0, 0, 0);
  };

  for(int it=0; it<32; it++){
    const int buf = it & 1;
    if(it < 31) stage(it+1, buf^1);    // only VM ops in the loop; async, never consumed
    kstep(it, buf);                    // pure LDS + VALU + MFMA
    asm volatile("s_waitcnt vmcnt(0)" ::: "memory");   // stage had a full kstep to land
    __builtin_amdgcn_s_barrier();
  }

  const int orow0 = r0 + 16*w + 4*kg;
  const int orow1 = orow0 + 64;
  const int ocol  = la;
  if constexpr (PART){
    float* pv = pv_out + (size_t)chunk*GN*GOUT;
    float* sp = s_out  + (size_t)chunk*GN;
    #pragma unroll
    for(int t=0;t<16;t++){
      #pragma unroll
      for(int r=0;r<4;r++){
        pv[(size_t)(orow0 + r)*GOUT + ocol + 16*t] = acc0[t][r];
        pv[(size_t)(orow1 + r)*GOUT + ocol + 16*t] = acc1[t][r];
      }
    }
    if(ocol == 0){
      #pragma unroll
      for(int r=0;r<4;r++){ sp[orow0 + r] = accs0[r]; sp[orow1 + r] = accs1[r]; }
    }
  } else {
    #pragma unroll
    for(int t=0;t<16;t++){
      #pragma unroll
      for(int r=0;r<4;r++){
        atomicAdd(pv_out + (size_t)(orow0 + r)*GOUT + ocol + 16*t, acc0[t][r]);
        atomicAdd(pv_out + (size_t)(orow1 + r)*GOUT + ocol + 16*t, acc1[t][r]);
      }
    }
    if(ocol == 0){
      #pragma unroll
      for(int r=0;r<4;r++){ atomicAdd(s_out + orow0 + r, accs0[r]); atomicAdd(s_out + orow1 + r, accs1[r]); }
    }
  }
}

// ---------------- epilogues ----------------
static __device__ __forceinline__ float elu1(float x){
  return x > 0.f ? x : (exp2f(x*LOG2E) - 1.f);
}

__global__ void k_reduce(const float* __restrict__ accP, const float* __restrict__ accSp,
                         float* __restrict__ out){
  size_t i = ((size_t)blockIdx.x*256 + threadIdx.x)*4;
  int row = (int)(i >> 8);
  float S = 0.f;
  #pragma unroll
  for(int c=0;c<8;c++) S += accSp[(size_t)c*GN + row];
  float4 s = {0.f,0.f,0.f,0.f};
  #pragma unroll
  for(int c=0;c<8;c++){
    float4 v = *(const float4*)(accP + (size_t)c*GN*GOUT + i);
    s.x += v.x; s.y += v.y; s.z += v.z; s.w += v.w;
  }
  float inv = 1.0f / S;
  float4 o;
  o.x = elu1(s.x*inv); o.y = elu1(s.y*inv); o.z = elu1(s.z*inv); o.w = elu1(s.w*inv);
  *(float4*)(out + i) = o;
}

__global__ void k_norm(const float* __restrict__ accPV, const float* __restrict__ accS,
                       float* __restrict__ out){
  size_t i = ((size_t)blockIdx.x*256 + threadIdx.x)*4;
  int row = (int)(i >> 8);
  float inv = 1.0f / accS[row];
  float4 v = *(const float4*)(accPV + i);
  float4 o;
  o.x = elu1(v.x*inv); o.y = elu1(v.y*inv); o.z = elu1(v.z*inv); o.w = elu1(v.w*inv);
  *(float4*)(out + i) = o;
}

// ---------------- launch ----------------
extern "C" void kernel_launch(void* const* d_in, const int* in_sizes, int n_in,
                              void* d_out, int out_size, void* d_ws, size_t ws_size,
                              hipStream_t stream){
  const float* h  = (const float*)d_in[0];
  const int*   adj= (const int*)  d_in[1];
  const float* W  = (const float*)d_in[2];
  const float* al = (const float*)d_in[3];
  const float* ar = (const float*)d_in[4];
  float* out = (float*)d_out;
  char* ws = (char*)d_ws;

  const size_t SZ_ACCP = (size_t)8*GN*GOUT*4;        // 67,108,864
  const size_t NEED_A  = SZ_ACCP + 4194304 + 32768 + 32768 + 262144; // 71,630,848

  if(ws_size >= NEED_A){
    float*  accP  = (float*) (ws);
    __bf16* hb    = (__bf16*)(ws);                       // alias (prep-only)
    __bf16* WT    = (__bf16*)(ws + 8388608);             // alias (prep-only)
    float*  wal   = (float*) (ws + 8650752);             // alias (prep-only)
    float*  war   = (float*) (ws + 8652800);             // alias (prep-only)
    __bf16* WhbT  = (__bf16*)(ws + SZ_ACCP);
    float*  Wh1   = (float*) (ws + SZ_ACCP + 4194304);
    float*  Wh2   = (float*) (ws + SZ_ACCP + 4227072);
    float*  accSp = (float*) (ws + SZ_ACCP + 4259840);

    k_pre1<<<2208, 256, 0, stream>>>(W, al, ar, h, wal, war, WT, hb);
    k_pre2<<<2304, 256, 0, stream>>>(WT, hb, WhbT, h, wal, war, Wh1, Wh2);
    k_attn<true><<<512, 256, 0, stream>>>(adj, WhbT, Wh1, Wh2, accP, accSp);
    k_reduce<<<2048, 256, 0, stream>>>(accP, accSp, out);
  } else {
    float*  accPV = (float*) (ws);                       //  8,388,608
    float*  accS  = (float*) (ws + 8388608);             //     32,768
    __bf16* hb    = (__bf16*)(ws + 8421376);             //  8,388,608
    __bf16* WT    = (__bf16*)(ws + 16809984);            //    262,144
    __bf16* WhbT  = (__bf16*)(ws + 17072128);            //  4,194,304
    float*  wal   = (float*) (ws + 21266432);
    float*  war   = (float*) (ws + 21268480);
    float*  Wh1   = (float*) (ws + 21270528);
    float*  Wh2   = (float*) (ws + 21303296);
    if(ws_size < 21336064) return;

    hipMemsetAsync(accPV, 0, 8388608 + 32768, stream);
    k_pre1<<<2208, 256, 0, stream>>>(W, al, ar, h, wal, war, WT, hb);
    k_pre2<<<2304, 256, 0, stream>>>(WT, hb, WhbT, h, wal, war, Wh1, Wh2);
    k_attn<false><<<512, 256, 0, stream>>>(adj, WhbT, Wh1, Wh2, accPV, accS);
    k_norm<<<2048, 256, 0, stream>>>(accPV, accS, out);
  }
}

// Round 13
// 128.928 us; speedup vs baseline: 1.1113x; 1.0067x over previous
//
#include <hip/hip_runtime.h>
#include <hip/hip_bf16.h>
#include <cstdint>
#include <cstddef>

typedef float  f32x4  __attribute__((ext_vector_type(4)));
typedef __bf16 bf16x8 __attribute__((ext_vector_type(8)));

#define LOG2E 1.4426950408889634f

static constexpr int GN   = 8192;   // nodes
static constexpr int GIN  = 512;    // in features
static constexpr int GOUT = 256;    // out features

// ---------------- async global->LDS (width 16) ----------------
static __device__ __forceinline__ void gload_lds16(const void* g, void* lds){
  typedef uint32_t __attribute__((address_space(1)))* gp_t;
  typedef uint32_t __attribute__((address_space(3)))* lp_t;
  __builtin_amdgcn_global_load_lds((gp_t)(uintptr_t)g,
                                   (lp_t)(uint32_t)(uintptr_t)lds, 16, 0, 0);
}

// ================= L1: [wal/war: 128 blk][W-transpose: 32 blk][h->bf16: 2048 blk] ====
__global__ __launch_bounds__(256) void k_pre1(const float* __restrict__ W,
                                              const float* __restrict__ al,
                                              const float* __restrict__ ar,
                                              const float* __restrict__ h,
                                              float* __restrict__ wal,
                                              float* __restrict__ war,
                                              __bf16* __restrict__ WT,
                                              __bf16* __restrict__ hb){
  __shared__ float T[64][65];
  const int bid = blockIdx.x, tid = threadIdx.x;
  if(bid < 128){
    const int k = bid*4 + (tid>>6), lane = tid & 63;
    float4 wv = ((const float4*)(W + (size_t)k*GOUT))[lane];
    float4 av = ((const float4*)al)[lane];
    float4 bv = ((const float4*)ar)[lane];
    float sl = wv.x*av.x + wv.y*av.y + wv.z*av.z + wv.w*av.w;
    float sr = wv.x*bv.x + wv.y*bv.y + wv.z*bv.z + wv.w*bv.w;
    #pragma unroll
    for(int o=32;o;o>>=1){ sl += __shfl_down(sl,o,64); sr += __shfl_down(sr,o,64); }
    if(lane==0){ wal[k] = sl*LOG2E; war[k] = sr*LOG2E; }
  } else if(bid < 160){
    const int tile = bid - 128;
    const int k0 = (tile>>2)*64, c0 = (tile&3)*64;
    const int r = tid>>2, cs = (tid&3)*16;
    #pragma unroll
    for(int j=0;j<4;j++){
      float4 v = *(const float4*)(W + (size_t)(k0+r)*GOUT + c0 + cs + 4*j);
      T[r][cs+4*j+0]=v.x; T[r][cs+4*j+1]=v.y; T[r][cs+4*j+2]=v.z; T[r][cs+4*j+3]=v.w;
    }
    __syncthreads();
    bf16x8 o1, o2;
    #pragma unroll
    for(int j=0;j<8;j++){ o1[j]=(__bf16)T[cs+j][r]; o2[j]=(__bf16)T[cs+8+j][r]; }
    __bf16* dst = WT + (size_t)(c0+r)*GIN + k0 + cs;
    *(bf16x8*)dst = o1;
    *(bf16x8*)(dst+8) = o2;
  } else {
    size_t i = ((size_t)(bid-160)*256 + tid)*8;
    float4 v0 = *(const float4*)(h+i);
    float4 v1 = *(const float4*)(h+i+4);
    bf16x8 o;
    o[0]=(__bf16)v0.x; o[1]=(__bf16)v0.y; o[2]=(__bf16)v0.z; o[3]=(__bf16)v0.w;
    o[4]=(__bf16)v1.x; o[5]=(__bf16)v1.y; o[6]=(__bf16)v1.z; o[7]=(__bf16)v1.w;
    *(bf16x8*)(hb+i) = o;
  }
}

// ================= L2: [gemmT: 256][Wh12: 2048] ============
__global__ __launch_bounds__(256) void k_pre2(const __bf16* __restrict__ WT,
                                              const __bf16* __restrict__ hb,
                                              __bf16* __restrict__ WhbT,
                                              const float* __restrict__ h,
                                              const float* __restrict__ wal,
                                              const float* __restrict__ war,
                                              float* __restrict__ Wh1,
                                              float* __restrict__ Wh2){
  __shared__ __attribute__((aligned(16))) __bf16 As[2][64*64];
  __shared__ __attribute__((aligned(16))) __bf16 Bs[2][128*64];
  const int bid = blockIdx.x, tid = threadIdx.x;
  const int lane = tid & 63, w = tid >> 6;

  if(bid < 256){
    const int mb = bid >> 6, nb = bid & 63;
    const int m0 = mb*64, n0 = nb*128;

    f32x4 acc[8];
    #pragma unroll
    for(int t=0;t<8;t++) acc[t] = (f32x4){0.f,0.f,0.f,0.f};

    const int lr = lane>>3;
    const int bs_sw = ((lane&7)*16) ^ (lr<<4);

    auto stage = [&](int it, int buf){
      const int k0b = it*128;
      #pragma unroll
      for(int s=0;s<6;s++){
        int u = w + s*4;
        const char* src; char* dst;
        if(u < 8){
          int r8 = u*8;
          src = (const char*)(WT + (size_t)(m0 + r8 + lr)*GIN);
          dst = (char*)&As[buf][0] + r8*128;
        } else {
          int r8 = (u-8)*8;
          src = (const char*)(hb + (size_t)(n0 + r8 + lr)*GIN);
          dst = (char*)&Bs[buf][0] + r8*128;
        }
        gload_lds16(src + k0b + bs_sw, dst);
      }
    };

    auto kstep = [&](int kk, int buf){
      const int ko = kk*64 + (lane>>4)*16;
      const int am = 16*w + (lane&15);
      bf16x8 af = *(const bf16x8*)((const char*)&As[buf][0] + am*128 + (ko ^ ((am&7)<<4)));
      #pragma unroll
      for(int t=0;t<8;t++){
        int n = 16*t + (lane&15);
        bf16x8 bf = *(const bf16x8*)((const char*)&Bs[buf][0] + n*128 + (ko ^ ((n&7)<<4)));
        acc[t] = __builtin_amdgcn_mfma_f32_16x16x32_bf16(af, bf, acc[t], 0, 0, 0);
      }
    };

    stage(0,0);
    asm volatile("s_waitcnt vmcnt(0)" ::: "memory");
    __builtin_amdgcn_s_barrier();
    for(int it=0; it<8; it++){
      int buf = it & 1;
      if(it < 7) stage(it+1, buf^1);
      kstep(0, buf);
      kstep(1, buf);
      asm volatile("s_waitcnt vmcnt(0)" ::: "memory");
      __builtin_amdgcn_s_barrier();
    }

    const int mrow = m0 + 16*w + 4*(lane>>4);
    const int nc0  = n0 + (lane&15);
    #pragma unroll
    for(int t=0;t<8;t++){
      #pragma unroll
      for(int r=0;r<4;r++){
        WhbT[(size_t)(mrow + r)*GN + nc0 + 16*t] = (__bf16)acc[t][r];
      }
    }
  } else {
    const int row = (bid-256)*4 + w;
    const float4* hp = (const float4*)(h + (size_t)row*GIN);
    float4 v0 = hp[lane*2], v1 = hp[lane*2+1];
    float4 a0 = ((const float4*)wal)[lane*2], a1 = ((const float4*)wal)[lane*2+1];
    float4 b0 = ((const float4*)war)[lane*2], b1 = ((const float4*)war)[lane*2+1];
    float sl = v0.x*a0.x+v0.y*a0.y+v0.z*a0.z+v0.w*a0.w
             + v1.x*a1.x+v1.y*a1.y+v1.z*a1.z+v1.w*a1.w;
    float sr = v0.x*b0.x+v0.y*b0.y+v0.z*b0.z+v0.w*b0.w
             + v1.x*b1.x+v1.y*b1.y+v1.z*b1.z+v1.w*b1.w;
    #pragma unroll
    for(int of=32;of;of>>=1){ sl += __shfl_down(sl,of,64); sr += __shfl_down(sr,of,64); }
    if(lane==0){ Wh1[row]=sl; Wh2[row]=sr; }
  }
}

// ================= fused pack + masked-softmax-attention =================
// grid 512: rg=bid>>3 (64 rowgroups of 128), chunk=bid&7 (1024 cols; chunk->XCD).
// PACK: linear 1KB bursts, now 4-DEEP row pipeline (A0..A3, statically indexed) —
// pack(r) frees its buffer and immediately reloads r+4 into it, so every row's
// loads get ~3 pack-periods (>latency) to land; >=12KB/wave stays outstanding.
// Ballot-native mask word (bit 8b+a <-> col 4a+b); mkL XOR-swizzled (row^jw).
// Main loop / V path / epilogue identical to r12 (verified).
template<bool PART>
__global__ __launch_bounds__(256,2) void k_attn(const int* __restrict__ adj,
                                                const __bf16* __restrict__ WhbT,
                                                const float* __restrict__ Wh1s,
                                                const float* __restrict__ Wh2s,
                                                float* __restrict__ pv_out,
                                                float* __restrict__ s_out){
  __shared__ __attribute__((aligned(16))) char Vs[2][16384];
  __shared__ __attribute__((aligned(16))) unsigned int mkL[32*128];
  __shared__ __attribute__((aligned(16))) float wh2L[1024];
  const int tid = threadIdx.x, lane = tid & 63, w = tid >> 6;
  const int rg = blockIdx.x >> 3, chunk = blockIdx.x & 7;
  const int r0 = rg * 128;
  const int j0 = chunk * 1024;
  const int la = lane & 15, kg = lane >> 4, kg8 = kg << 3;

  // ---- early reg-loads (wh2 strip + wh1) ----
  float4 wv = *(const float4*)(Wh2s + j0 + tid*4);
  const float wh1_0 = Wh1s[r0 + 16*w + la];        // pre-scaled by log2(e)
  const float wh1_1 = Wh1s[r0 + 16*w + la + 64];

  // V stage: linear LDS dest, inverse-swizzled global src (r9-r12 layout, verified)
  const int l_log = (lane&7) ^ (lane>>3);
  const char* wbase = (const char*)WhbT
                    + (size_t)(64*w + 2*(lane>>3) + (l_log>>2))*(GN*2)
                    + (size_t)(l_log&3)*16;
  auto stage = [&](int it, int buf){
    const size_t colb = (size_t)(j0 + it*32)*2;
    char* dst = &Vs[buf][0] + w*4096 + lane*16;
    #pragma unroll
    for(int s=0;s<4;s++){
      gload_lds16(wbase + (size_t)(16*s)*(GN*2) + colb, dst + s*1024);
    }
  };

  stage(0, 0);                       // V(0) rides along under the adj streaming below

  // ---- fused pack, linear-burst, 4-deep row pipeline ----
  {
    const size_t abase = (size_t)(r0 + 32*w)*GN + j0;
    const int idx = lane & 31;
    const int shift = (idx & 7) * 8;
    const bool qb0 = (idx >> 3) & 1, qb1 = (idx >> 4) & 1;
    int4 A0[4], A1[4], A2[4], A3[4];
    auto rload = [&](int r, int4 (&A)[4]){
      const int* p = adj + abase + (size_t)r*GN + lane*4;
      #pragma unroll
      for(int q=0;q<4;q++) A[q] = *(const int4*)(p + q*256);
    };
    auto rpack = [&](int r, int4 (&A)[4]){
      uint64_t B00 = __ballot(A[0].x!=0), B01 = __ballot(A[0].y!=0),
               B02 = __ballot(A[0].z!=0), B03 = __ballot(A[0].w!=0);
      uint64_t B10 = __ballot(A[1].x!=0), B11 = __ballot(A[1].y!=0),
               B12 = __ballot(A[1].z!=0), B13 = __ballot(A[1].w!=0);
      uint64_t B20 = __ballot(A[2].x!=0), B21 = __ballot(A[2].y!=0),
               B22 = __ballot(A[2].z!=0), B23 = __ballot(A[2].w!=0);
      uint64_t B30 = __ballot(A[3].x!=0), B31 = __ballot(A[3].y!=0),
               B32 = __ballot(A[3].z!=0), B33 = __ballot(A[3].w!=0);
      uint64_t u0 = qb1 ? (qb0? B30:B20) : (qb0? B10:B00);
      uint64_t u1 = qb1 ? (qb0? B31:B21) : (qb0? B11:B01);
      uint64_t u2 = qb1 ? (qb0? B32:B22) : (qb0? B12:B02);
      uint64_t u3 = qb1 ? (qb0? B33:B23) : (qb0? B13:B03);
      unsigned int word = ((unsigned int)(u0 >> shift) & 0xffu)
                        | (((unsigned int)(u1 >> shift) & 0xffu) << 8)
                        | (((unsigned int)(u2 >> shift) & 0xffu) << 16)
                        | (((unsigned int)(u3 >> shift) & 0xffu) << 24);
      if(lane < 32){
        const int row = 32*w + r;
        mkL[idx*128 + (row ^ idx)] = word;     // XOR-swizzle: store conflict-free
      }
    };
    rload(0, A0); rload(1, A1); rload(2, A2); rload(3, A3);
    #pragma unroll 1
    for(int rq=0; rq<8; ++rq){
      const int r = 4*rq;
      rpack(r+0, A0); if(rq<7) rload(r+4, A0);
      rpack(r+1, A1); if(rq<7) rload(r+5, A1);
      rpack(r+2, A2); if(rq<7) rload(r+6, A2);
      rpack(r+3, A3); if(rq<7) rload(r+7, A3);
    }
  }

  *(float4*)&wh2L[tid*4] = wv;

  f32x4 acc0[16], acc1[16];
  #pragma unroll
  for(int t=0;t<16;t++){ acc0[t] = (f32x4){0.f,0.f,0.f,0.f}; acc1[t] = (f32x4){0.f,0.f,0.f,0.f}; }
  f32x4 accs0 = (f32x4){0.f,0.f,0.f,0.f};
  f32x4 accs1 = (f32x4){0.f,0.f,0.f,0.f};
  bf16x8 ones;
  #pragma unroll
  for(int j=0;j<8;j++) ones[j] = (__bf16)1.0f;

  __syncthreads();                   // drains stage(0) + mask/wh2 LDS fills

  // ballot-native bit order: pa[e] <- bit 8*(e&3)+(e>>2) of (m32 >> 2kg)
  auto mkpa = [&](float wh1, unsigned mm, float4 w0, float4 w1) -> bf16x8 {
    bf16x8 pa;
    float y, p;
    y = wh1 + w0.x; y = fmaxf(y, 0.2f*y); p = exp2f(y); pa[0] = (__bf16)((mm    )&1 ? p : 0.f);
    y = wh1 + w0.y; y = fmaxf(y, 0.2f*y); p = exp2f(y); pa[1] = (__bf16)((mm>>8 )&1 ? p : 0.f);
    y = wh1 + w0.z; y = fmaxf(y, 0.2f*y); p = exp2f(y); pa[2] = (__bf16)((mm>>16)&1 ? p : 0.f);
    y = wh1 + w0.w; y = fmaxf(y, 0.2f*y); p = exp2f(y); pa[3] = (__bf16)((mm>>24)&1 ? p : 0.f);
    y = wh1 + w1.x; y = fmaxf(y, 0.2f*y); p = exp2f(y); pa[4] = (__bf16)((mm>>1 )&1 ? p : 0.f);
    y = wh1 + w1.y; y = fmaxf(y, 0.2f*y); p = exp2f(y); pa[5] = (__bf16)((mm>>9 )&1 ? p : 0.f);
    y = wh1 + w1.z; y = fmaxf(y, 0.2f*y); p = exp2f(y); pa[6] = (__bf16)((mm>>17)&1 ? p : 0.f);
    y = wh1 + w1.w; y = fmaxf(y, 0.2f*y); p = exp2f(y); pa[7] = (__bf16)((mm>>25)&1 ? p : 0.f);
    return pa;
  };

  // per-lane read base into V tile (pair-row + XOR slot), +t*1024 folds to immediate
  const int rd_off = (la>>1)*128 + (((((la&1)<<2) | kg) ^ (la>>1)) << 4);
  const int kg2 = 2*kg;

  auto kstep = [&](int it, int buf){
    unsigned int m0 = mkL[it*128 + ((16*w + la) ^ it)];
    unsigned int m1 = mkL[it*128 + ((16*w + la + 64) ^ it)];
    const float* wp = &wh2L[it*32 + kg8];
    float4 w0 = *(const float4*)wp;
    float4 w1 = *(const float4*)(wp + 4);
    bf16x8 pa0 = mkpa(wh1_0, m0 >> kg2, w0, w1);
    bf16x8 pa1 = mkpa(wh1_1, m1 >> kg2, w0, w1);
    const char* vb = &Vs[buf][0] + rd_off;
    #pragma unroll
    for(int t=0;t<16;t++){
      bf16x8 bv = *(const bf16x8*)(vb + t*1024);
      acc0[t] = __builtin_amdgcn_mfma_f32_16x16x32_bf16(pa0, bv, acc0[t], 0, 0, 0);
      acc1[t] = __builtin_amdgcn_mfma_f32_16x16x32_bf16(pa1, bv, acc1[t], 0, 0, 0);
    }
    accs0 = __builtin_amdgcn_mfma_f32_16x16x32_bf16(pa0, ones, accs0, 0, 0, 0);
    accs1 = __builtin_amdgcn_mfma_f32_16x16x32_bf16(pa1, ones, accs1, 0, 0, 0);
  };

  for(int it=0; it<32; it++){
    const int buf = it & 1;
    if(it < 31) stage(it+1, buf^1);    // only VM ops in the loop; async, never consumed
    kstep(it, buf);                    // pure LDS + VALU + MFMA
    asm volatile("s_waitcnt vmcnt(0)" ::: "memory");   // stage had a full kstep to land
    __builtin_amdgcn_s_barrier();
  }

  const int orow0 = r0 + 16*w + 4*kg;
  const int orow1 = orow0 + 64;
  const int ocol  = la;
  if constexpr (PART){
    float* pv = pv_out + (size_t)chunk*GN*GOUT;
    float* sp = s_out  + (size_t)chunk*GN;
    #pragma unroll
    for(int t=0;t<16;t++){
      #pragma unroll
      for(int r=0;r<4;r++){
        pv[(size_t)(orow0 + r)*GOUT + ocol + 16*t] = acc0[t][r];
        pv[(size_t)(orow1 + r)*GOUT + ocol + 16*t] = acc1[t][r];
      }
    }
    if(ocol == 0){
      #pragma unroll
      for(int r=0;r<4;r++){ sp[orow0 + r] = accs0[r]; sp[orow1 + r] = accs1[r]; }
    }
  } else {
    #pragma unroll
    for(int t=0;t<16;t++){
      #pragma unroll
      for(int r=0;r<4;r++){
        atomicAdd(pv_out + (size_t)(orow0 + r)*GOUT + ocol + 16*t, acc0[t][r]);
        atomicAdd(pv_out + (size_t)(orow1 + r)*GOUT + ocol + 16*t, acc1[t][r]);
      }
    }
    if(ocol == 0){
      #pragma unroll
      for(int r=0;r<4;r++){ atomicAdd(s_out + orow0 + r, accs0[r]); atomicAdd(s_out + orow1 + r, accs1[r]); }
    }
  }
}

// ---------------- epilogues ----------------
static __device__ __forceinline__ float elu1(float x){
  return x > 0.f ? x : (exp2f(x*LOG2E) - 1.f);
}

__global__ void k_reduce(const float* __restrict__ accP, const float* __restrict__ accSp,
                         float* __restrict__ out){
  size_t i = ((size_t)blockIdx.x*256 + threadIdx.x)*4;
  int row = (int)(i >> 8);
  float S = 0.f;
  #pragma unroll
  for(int c=0;c<8;c++) S += accSp[(size_t)c*GN + row];
  float4 s = {0.f,0.f,0.f,0.f};
  #pragma unroll
  for(int c=0;c<8;c++){
    float4 v = *(const float4*)(accP + (size_t)c*GN*GOUT + i);
    s.x += v.x; s.y += v.y; s.z += v.z; s.w += v.w;
  }
  float inv = 1.0f / S;
  float4 o;
  o.x = elu1(s.x*inv); o.y = elu1(s.y*inv); o.z = elu1(s.z*inv); o.w = elu1(s.w*inv);
  *(float4*)(out + i) = o;
}

__global__ void k_norm(const float* __restrict__ accPV, const float* __restrict__ accS,
                       float* __restrict__ out){
  size_t i = ((size_t)blockIdx.x*256 + threadIdx.x)*4;
  int row = (int)(i >> 8);
  float inv = 1.0f / accS[row];
  float4 v = *(const float4*)(accPV + i);
  float4 o;
  o.x = elu1(v.x*inv); o.y = elu1(v.y*inv); o.z = elu1(v.z*inv); o.w = elu1(v.w*inv);
  *(float4*)(out + i) = o;
}

// ---------------- launch ----------------
extern "C" void kernel_launch(void* const* d_in, const int* in_sizes, int n_in,
                              void* d_out, int out_size, void* d_ws, size_t ws_size,
                              hipStream_t stream){
  const float* h  = (const float*)d_in[0];
  const int*   adj= (const int*)  d_in[1];
  const float* W  = (const float*)d_in[2];
  const float* al = (const float*)d_in[3];
  const float* ar = (const float*)d_in[4];
  float* out = (float*)d_out;
  char* ws = (char*)d_ws;

  const size_t SZ_ACCP = (size_t)8*GN*GOUT*4;        // 67,108,864
  const size_t NEED_A  = SZ_ACCP + 4194304 + 32768 + 32768 + 262144; // 71,630,848

  if(ws_size >= NEED_A){
    float*  accP  = (float*) (ws);
    __bf16* hb    = (__bf16*)(ws);                       // alias (prep-only)
    __bf16* WT    = (__bf16*)(ws + 8388608);             // alias (prep-only)
    float*  wal   = (float*) (ws + 8650752);             // alias (prep-only)
    float*  war   = (float*) (ws + 8652800);             // alias (prep-only)
    __bf16* WhbT  = (__bf16*)(ws + SZ_ACCP);
    float*  Wh1   = (float*) (ws + SZ_ACCP + 4194304);
    float*  Wh2   = (float*) (ws + SZ_ACCP + 4227072);
    float*  accSp = (float*) (ws + SZ_ACCP + 4259840);

    k_pre1<<<2208, 256, 0, stream>>>(W, al, ar, h, wal, war, WT, hb);
    k_pre2<<<2304, 256, 0, stream>>>(WT, hb, WhbT, h, wal, war, Wh1, Wh2);
    k_attn<true><<<512, 256, 0, stream>>>(adj, WhbT, Wh1, Wh2, accP, accSp);
    k_reduce<<<2048, 256, 0, stream>>>(accP, accSp, out);
  } else {
    float*  accPV = (float*) (ws);                       //  8,388,608
    float*  accS  = (float*) (ws + 8388608);             //     32,768
    __bf16* hb    = (__bf16*)(ws + 8421376);             //  8,388,608
    __bf16* WT    = (__bf16*)(ws + 16809984);            //    262,144
    __bf16* WhbT  = (__bf16*)(ws + 17072128);            //  4,194,304
    float*  wal   = (float*) (ws + 21266432);
    float*  war   = (float*) (ws + 21268480);
    float*  Wh1   = (float*) (ws + 21270528);
    float*  Wh2   = (float*) (ws + 21303296);
    if(ws_size < 21336064) return;

    hipMemsetAsync(accPV, 0, 8388608 + 32768, stream);
    k_pre1<<<2208, 256, 0, stream>>>(W, al, ar, h, wal, war, WT, hb);
    k_pre2<<<2304, 256, 0, stream>>>(WT, hb, WhbT, h, wal, war, Wh1, Wh2);
    k_attn<false><<<512, 256, 0, stream>>>(adj, WhbT, Wh1, Wh2, accPV, accS);
    k_norm<<<2048, 256, 0, stream>>>(accPV, accS, out);
  }
}